// Round 3
// baseline (671.316 us; speedup 1.0000x reference)
//
#include <hip/hip_runtime.h>
#include <hip/hip_bf16.h>

// Problem constants: B=4, C=64, F=256, T=256, CH=32
typedef __hip_bfloat16 bf16;
typedef __attribute__((ext_vector_type(8))) short bf16x8;
typedef __attribute__((ext_vector_type(4))) float f32x4;
typedef __attribute__((ext_vector_type(8))) unsigned short u16x8;
typedef __attribute__((ext_vector_type(4))) unsigned int u32x4;

struct ConvP {
  const float* W; const float* bi; const float* g; const float* be;
  const float* m; const float* v; const float* a;
};

__device__ __forceinline__ unsigned short f2bf(float f) {
  __hip_bfloat16 h = __float2bfloat16(f);
  return __builtin_bit_cast(unsigned short, h);
}
__device__ __forceinline__ float bf2f(unsigned short u) {
  return __uint_as_float(((unsigned)u) << 16);
}

// ---------------------------------------------------------------------------
// Kernel A: fused 1x1 conv + BN + LeakyReLU for fqk (inp), tqk (inp), fv (x).
// Grid 1024 = (b,f), 256 threads = t. v3 structure:
//  - input tile (64 c x 256 t fp32) staged once in LDS (64 KB) -> no global
//    rematerialization (round-2 FETCH was 233 MB vs 134 ideal from re-reads)
//  - o-outer compute: xi[64] in VGPRs, W via uniform s_loads (SMEM pipe),
//    inner loop is pure v_fmac with SGPR operand
//  - outputs staged in swizzled 16 KB LDS tile, then streamed out lane-dense
//    (16 B/lane -> full 128 B lines per instruction; round-2's 64 B-stride
//    partial-sector stores caused 223 MB WRITE vs 84 ideal)
// ---------------------------------------------------------------------------
__global__ __launch_bounds__(256, 2) void conv_qkv(
    const float* __restrict__ inp, const float* __restrict__ x,
    ConvP fqk, ConvP fv, ConvP tqk,
    bf16* __restrict__ Qf, bf16* __restrict__ Kf, bf16* __restrict__ Vf,
    bf16* __restrict__ Qt, bf16* __restrict__ Kt)
{
  __shared__ __attribute__((aligned(16))) float lin[64 * 256];      // 64 KB (c-major)
  __shared__ __attribute__((aligned(16))) unsigned int outs32[4096]; // 16 KB staging

  const int tid = threadIdx.x;
  const int b = blockIdx.x >> 8;
  const int f = blockIdx.x & 255;
  const int inoff = b * 64 * 65536 + f * 256 + tid;   // (b,c=0,f,t=tid)
  const size_t tbase = (size_t)(b * 256 + f) * 8192;  // tile base (elements)
  const int swz = (tid ^ (tid >> 2)) & 3;

  // stage one output tile (16 KB) from pack regs and stream it out lane-dense
  auto emit_tile = [&](const unsigned int* pack, bf16* dst) {
    __syncthreads();   // previous tile's streaming reads done
    #pragma unroll
    for (int j = 0; j < 16; ++j)
      outs32[tid * 16 + (((j >> 2) ^ swz) << 2) + (j & 3)] = pack[j];
    __syncthreads();
    #pragma unroll
    for (int k = 0; k < 4; ++k) {
      const int chunk = k * 256 + tid;          // 0..1023 (16 B units)
      const int t = chunk >> 2, qi = chunk & 3;
      const int sw = (t ^ (t >> 2)) & 3;
      u32x4 v = *(const u32x4*)&outs32[t * 16 + ((qi ^ sw) << 2)];
      *(u32x4*)(dst + tbase + (size_t)chunk * 8) = v;
    }
  };

  // ---- stage inp tile ----
  #pragma unroll 4
  for (int c = 0; c < 64; ++c) lin[c * 256 + tid] = inp[inoff + c * 65536];
  __syncthreads();

  float xi[64];
  #pragma unroll
  for (int i = 0; i < 64; ++i) xi[i] = lin[i * 256 + tid];

  // ---- fqk and tqk passes (both read xi = inp tile) ----
  #pragma unroll 1
  for (int which = 0; which < 2; ++which) {
    const ConvP& P = which ? tqk : fqk;
    const float alpha = P.a[0];
    unsigned int packQ[16], packK[16];
    #pragma unroll 2
    for (int o2 = 0; o2 < 32; ++o2) {
      float yqk[2];
      #pragma unroll
      for (int s = 0; s < 2; ++s) {
        const int o = 2 * o2 + s;
        const float* w = P.W + o * 64;
        float a0 = 0.f, a1 = 0.f, a2 = 0.f, a3 = 0.f;
        #pragma unroll
        for (int i = 0; i < 64; i += 4) {
          a0 += w[i] * xi[i];     a1 += w[i + 1] * xi[i + 1];
          a2 += w[i + 2] * xi[i + 2]; a3 += w[i + 3] * xi[i + 3];
        }
        const float acc = (a0 + a1) + (a2 + a3);
        const float A = P.g[o] * rsqrtf(P.v[o] + 1e-5f);
        float y = (acc + P.bi[o] - P.m[o]) * A + P.be[o];
        yqk[s] = y > 0.f ? y : alpha * y;
      }
      const unsigned short hq = f2bf(yqk[0]), hk = f2bf(yqk[1]);
      if (o2 & 1) { packQ[o2 >> 1] |= ((unsigned)hq) << 16;
                    packK[o2 >> 1] |= ((unsigned)hk) << 16; }
      else        { packQ[o2 >> 1] = hq; packK[o2 >> 1] = hk; }
    }
    emit_tile(packQ, which ? Qt : Qf);
    emit_tile(packK, which ? Kt : Kf);
  }

  // ---- fv pass (reads x tile) ----
  __syncthreads();
  #pragma unroll 4
  for (int c = 0; c < 64; ++c) lin[c * 256 + tid] = x[inoff + c * 65536];
  __syncthreads();
  #pragma unroll
  for (int i = 0; i < 64; ++i) xi[i] = lin[i * 256 + tid];

  {
    const float alpha = fv.a[0];
    unsigned int packV[16];
    #pragma unroll 2
    for (int o2 = 0; o2 < 16; ++o2) {
      float yv[2];
      #pragma unroll
      for (int s = 0; s < 2; ++s) {
        const int o = 2 * o2 + s;
        const float* w = fv.W + o * 64;
        float a0 = 0.f, a1 = 0.f, a2 = 0.f, a3 = 0.f;
        #pragma unroll
        for (int i = 0; i < 64; i += 4) {
          a0 += w[i] * xi[i];     a1 += w[i + 1] * xi[i + 1];
          a2 += w[i + 2] * xi[i + 2]; a3 += w[i + 3] * xi[i + 3];
        }
        const float acc = (a0 + a1) + (a2 + a3);
        const float A = fv.g[o] * rsqrtf(fv.v[o] + 1e-5f);
        float y = (acc + fv.bi[o] - fv.m[o]) * A + fv.be[o];
        yv[s] = y > 0.f ? y : alpha * y;
      }
      packV[o2] = (unsigned)f2bf(yv[0]) | (((unsigned)f2bf(yv[1])) << 16);
    }
    emit_tile(packV, Vf);
  }
}

// ---------------------------------------------------------------------------
// Attention kernel: 1024 instances of [256 x 256, head dim 32].
// All buffers layout (B,F,T,CH).
//   CAUSAL (t-attn):  instance (b,f): row r at inst*8192 + r*32 (contiguous)
//   !CAUSAL (f-attn): instance (b,t): row r at b*2M + t*32 + r*8192 (strided)
// v3: K staged once per block in LDS (was re-read 16x from global = 268 MB);
// Q loaded per-wave sector-dense via 1 KB scratch; O staged in same scratch
// and streamed out sector-dense (was 2 B/lane scatter stores).
// ---------------------------------------------------------------------------
template<bool CAUSAL>
__global__ __launch_bounds__(256) void attn_k(
    const bf16* __restrict__ Qg, const bf16* __restrict__ Kg,
    const bf16* __restrict__ Vg, bf16* __restrict__ Og)
{
  __shared__ __attribute__((aligned(16))) unsigned short Kl[256 * 32];       // 16 KB dense
  __shared__ __attribute__((aligned(16))) unsigned short Vt[32 * 264];       // V^T, stride 264
  __shared__ __attribute__((aligned(16))) unsigned short Plds[4][16 * 264];  // per-wave P
  __shared__ __attribute__((aligned(16))) unsigned short Wsc[4][512];        // per-wave Q/O scratch

  const int inst = blockIdx.x;
  const int b = inst >> 8;
  const int s = inst & 255;
  constexpr int RS = CAUSAL ? 32 : 8192;             // row stride (elements)
  const int qbase = CAUSAL ? inst * 8192 : (b * 2097152 + s * 32);

  const int tid = threadIdx.x;
  // ---- stage K tile (sector-dense cooperative load) ----
  #pragma unroll
  for (int k2 = 0; k2 < 4; ++k2) {
    const int chunk = k2 * 256 + tid;            // 0..1023
    const int row = chunk >> 2, part = chunk & 3;
    u32x4 val = *(const u32x4*)(Kg + qbase + row * RS + part * 8);
    *(u32x4*)&Kl[row * 32 + part * 8] = val;
  }
  // ---- stage V transposed ----
  if (tid < 128) {
    const unsigned short* v0 = (const unsigned short*)(Vg + qbase) + (2 * tid) * RS;
    const unsigned short* v1 = v0 + RS;
    u16x8 a[4], c[4];
    #pragma unroll
    for (int q = 0; q < 4; ++q) {
      a[q] = *(const u16x8*)(v0 + 8 * q);
      c[q] = *(const u16x8*)(v1 + 8 * q);
    }
    unsigned int* vt32 = (unsigned int*)Vt;
    #pragma unroll
    for (int cc = 0; cc < 32; ++cc) {
      unsigned lo = a[cc >> 3][cc & 7];
      unsigned hi = c[cc >> 3][cc & 7];
      vt32[(cc * 264 + 2 * tid) >> 1] = lo | (hi << 16);
    }
  }
  __syncthreads();

  const int lane = tid & 63;
  const int wid = tid >> 6;
  const int m16 = lane & 15;
  const int quad = lane >> 4;
  const float sc = 0.17677669529663687f;   // 1/sqrt(32)

  unsigned short* P  = &Plds[wid][0];
  unsigned short* Ws = &Wsc[wid][0];
  const int r4 = lane >> 2, p4 = lane & 3;

  #pragma unroll 1
  for (int it = 0; it < 4; ++it) {
    const int rt = wid + 4 * it;
    // wave loads its Q tile sector-dense into private scratch, then frag-reads
    {
      u32x4 qv = *(const u32x4*)(Qg + qbase + (rt * 16 + r4) * RS + p4 * 8);
      *(u32x4*)&Ws[r4 * 32 + p4 * 8] = qv;
    }
    const bf16x8 qf = *(const bf16x8*)&Ws[m16 * 32 + quad * 8];
    const int nct = CAUSAL ? (rt + 1) : 16;

    f32x4 acc[16];
    #pragma unroll
    for (int ct = 0; ct < 16; ++ct) {
      if (ct < nct) {
        const bf16x8 kf = *(const bf16x8*)&Kl[(ct * 16 + m16) * 32 + quad * 8];
        f32x4 z = {0.f, 0.f, 0.f, 0.f};
        acc[ct] = __builtin_amdgcn_mfma_f32_16x16x32_bf16(qf, kf, z, 0, 0, 0);
      }
    }
    // scale + causal mask + row max (D layout: col=lane&15, row=quad*4+reg)
    float mx[4] = {-3e38f, -3e38f, -3e38f, -3e38f};
    #pragma unroll
    for (int ct = 0; ct < 16; ++ct) if (ct < nct) {
      #pragma unroll
      for (int r = 0; r < 4; ++r) {
        float v = acc[ct][r] * sc;
        if (CAUSAL && (ct == nct - 1) && (m16 > quad * 4 + r)) v = -3e38f;
        acc[ct][r] = v;
        mx[r] = fmaxf(mx[r], v);
      }
    }
    #pragma unroll
    for (int r = 0; r < 4; ++r) {
      float m = mx[r];
      #pragma unroll
      for (int d = 1; d < 16; d <<= 1) m = fmaxf(m, __shfl_xor(m, d, 16));
      mx[r] = m;
    }
    float sum[4] = {0.f, 0.f, 0.f, 0.f};
    #pragma unroll
    for (int ct = 0; ct < 16; ++ct) if (ct < nct) {
      #pragma unroll
      for (int r = 0; r < 4; ++r) {
        float p = __expf(acc[ct][r] - mx[r]);
        acc[ct][r] = p;
        sum[r] += p;
      }
    }
    float inv[4];
    #pragma unroll
    for (int r = 0; r < 4; ++r) {
      float ssum = sum[r];
      #pragma unroll
      for (int d = 1; d < 16; d <<= 1) ssum += __shfl_xor(ssum, d, 16);
      inv[r] = 1.0f / ssum;
    }
    // write normalized P (bf16) to per-wave LDS
    #pragma unroll
    for (int ct = 0; ct < 16; ++ct) if (ct < nct) {
      #pragma unroll
      for (int r = 0; r < 4; ++r)
        P[(quad * 4 + r) * 264 + ct * 16 + m16] = f2bf(acc[ct][r] * inv[r]);
    }
    int ksteps = CAUSAL ? ((rt >> 1) + 1) : 8;
    if (CAUSAL && ((rt & 1) == 0)) {
      // zero-pad tile ct=rt+1 so the K=32 MFMA step covering it reads zeros
      #pragma unroll
      for (int u = 0; u < 4; ++u) {
        const int e = lane + 64 * u;
        P[(e >> 4) * 264 + (rt + 1) * 16 + (e & 15)] = 0;
      }
    }
    // O = P * V  (A-frag: m=lane&15, k=quad*8+j; B-frag from Vt rows)
    f32x4 o0 = {0.f, 0.f, 0.f, 0.f}, o1 = {0.f, 0.f, 0.f, 0.f};
    #pragma unroll
    for (int ks = 0; ks < 8; ++ks) {
      if (ks < ksteps) {
        const bf16x8 pf  = *(const bf16x8*)&P[m16 * 264 + ks * 32 + quad * 8];
        const bf16x8 vf0 = *(const bf16x8*)&Vt[m16 * 264 + ks * 32 + quad * 8];
        const bf16x8 vf1 = *(const bf16x8*)&Vt[(16 + m16) * 264 + ks * 32 + quad * 8];
        o0 = __builtin_amdgcn_mfma_f32_16x16x32_bf16(pf, vf0, o0, 0, 0, 0);
        o1 = __builtin_amdgcn_mfma_f32_16x16x32_bf16(pf, vf1, o1, 0, 0, 0);
      }
    }
    // stage O tile in per-wave scratch, stream out sector-dense
    #pragma unroll
    for (int r = 0; r < 4; ++r) {
      Ws[(quad * 4 + r) * 32 + m16]      = f2bf(o0[r]);
      Ws[(quad * 4 + r) * 32 + 16 + m16] = f2bf(o1[r]);
    }
    {
      u32x4 ov = *(const u32x4*)&Ws[r4 * 32 + p4 * 8];
      *(u32x4*)(Og + qbase + (rt * 16 + r4) * RS + p4 * 8) = ov;
    }
  }
}

// ---------------------------------------------------------------------------
// Kernel D: proj conv (32->64) + BN + LeakyReLU + residual add. fp32 output.
// ---------------------------------------------------------------------------
__global__ __launch_bounds__(256) void proj_k(
    const bf16* __restrict__ tout, const float* __restrict__ x,
    ConvP pj, float* __restrict__ out)
{
  const int tid = threadIdx.x;
  const int b = blockIdx.x >> 8;
  const int f = blockIdx.x & 255;
  const unsigned short* tp =
      (const unsigned short*)tout + ((b * 256 + f) * 256 + tid) * 32;
  u16x8 tv[4];
  #pragma unroll
  for (int q = 0; q < 4; ++q) tv[q] = *(const u16x8*)(tp + 8 * q);
  float vin[32];
  #pragma unroll
  for (int c = 0; c < 32; ++c) vin[c] = bf2f(tv[c >> 3][c & 7]);
  const float alpha = pj.a[0];
  const int xoff = b * 64 * 65536 + f * 256 + tid;
  #pragma unroll 4
  for (int o = 0; o < 64; ++o) {
    float acc = 0.f;
    #pragma unroll
    for (int i = 0; i < 32; ++i) acc += pj.W[o * 32 + i] * vin[i];
    const float s = rsqrtf(pj.v[o] + 1e-5f);
    const float A = pj.g[o] * s;
    float y = (acc + pj.bi[o] - pj.m[o]) * A + pj.be[o];
    y = y > 0.f ? y : alpha * y;
    out[xoff + o * 65536] = y + x[xoff + o * 65536];
  }
}

extern "C" void kernel_launch(void* const* d_in, const int* in_sizes, int n_in,
                              void* d_out, int out_size, void* d_ws, size_t ws_size,
                              hipStream_t stream) {
  const float* inp = (const float*)d_in[0];
  const float* x   = (const float*)d_in[1];
  auto cp = [&](int i) {
    return ConvP{ (const float*)d_in[i],     (const float*)d_in[i + 1],
                  (const float*)d_in[i + 2], (const float*)d_in[i + 3],
                  (const float*)d_in[i + 4], (const float*)d_in[i + 5],
                  (const float*)d_in[i + 6] };
  };
  ConvP fqk = cp(2), fv = cp(9), tqk = cp(16), pj = cp(23);

  char* ws = (char*)d_ws;
  const size_t SZ = (size_t)4 * 256 * 256 * 32 * 2;  // 16 MiB per bf16 buffer
  bf16* Qf = (bf16*)(ws + 0 * SZ);   // (B,F,T,CH)
  bf16* Kf = (bf16*)(ws + 1 * SZ);
  bf16* Vf = (bf16*)(ws + 2 * SZ);
  bf16* Qt = (bf16*)(ws + 3 * SZ);
  bf16* Kt = (bf16*)(ws + 4 * SZ);
  bf16* Ft = (bf16*)(ws + 5 * SZ);   // fout (B,F,T,CH)
  bf16* To = (bf16*)(ws + 0 * SZ);   // tout reuses Qf (dead after f-attn)

  conv_qkv<<<1024, 256, 0, stream>>>(inp, x, fqk, fv, tqk, Qf, Kf, Vf, Qt, Kt);
  attn_k<false><<<1024, 256, 0, stream>>>(Qf, Kf, Vf, Ft);   // freq attention
  attn_k<true><<<1024, 256, 0, stream>>>(Qt, Kt, Ft, To);    // causal time attention
  proj_k<<<1024, 256, 0, stream>>>(To, x, pj, (float*)d_out);
}

// Round 4
// 355.736 us; speedup vs baseline: 1.8871x; 1.8871x over previous
//
#include <hip/hip_runtime.h>
#include <hip/hip_bf16.h>

// Problem constants: B=4, C=64, F=256, T=256, CH=32
typedef __hip_bfloat16 bf16;
typedef __attribute__((ext_vector_type(8))) short bf16x8;
typedef __attribute__((ext_vector_type(4))) float f32x4;
typedef __attribute__((ext_vector_type(8))) unsigned short u16x8;
typedef __attribute__((ext_vector_type(4))) unsigned int u32x4;
typedef __attribute__((ext_vector_type(2))) unsigned int u32x2;

struct ConvP {
  const float* W; const float* bi; const float* g; const float* be;
  const float* m; const float* v; const float* a;
};

__device__ __forceinline__ unsigned short f2bf(float f) {
  __hip_bfloat16 h = __float2bfloat16(f);
  return __builtin_bit_cast(unsigned short, h);
}
__device__ __forceinline__ float bf2f(unsigned short u) {
  return __uint_as_float(((unsigned)u) << 16);
}

// ---------------------------------------------------------------------------
// Kernel A (v4, MFMA): fused 1x1 conv + BN + LeakyReLU for fqk/tqk (inp) and
// fv (x). Per block (b,f): the conv is a 64x64(x32) GEMM over 256 positions.
//  - X tile staged once in LDS as bf16 [c][t] (stride 260 -> <=2-way bank use)
//  - W lives in MFMA A-fragments in VGPRs (loaded once per matrix from L2)
//  - D = W*X via 16x16x32 bf16 MFMA (m=o, n=t, k=c); BN+leaky fused in
//    epilogue via per-channel (scale,shift) table precomputed in LDS
//  - Q/K de-interleaved into 2 staging buffers, streamed out lane-dense
//    (round-3 write path: WRITE_SIZE == 86 MB ideal, keep it)
// This kills round-3's scalar-pipe W stall (VALUBusy 28% @ 2 waves/SIMD):
// the per-wave payload is only ~80 MFMA + LDS traffic -> memory-bound.
// ---------------------------------------------------------------------------
__global__ __launch_bounds__(256, 2) void conv_qkv(
    const float* __restrict__ inp, const float* __restrict__ x,
    ConvP fqk, ConvP fv, ConvP tqk,
    bf16* __restrict__ Qf, bf16* __restrict__ Kf, bf16* __restrict__ Vf,
    bf16* __restrict__ Qt, bf16* __restrict__ Kt)
{
  __shared__ __attribute__((aligned(16))) unsigned short Xb[64 * 260]; // 33.3 KB
  __shared__ __attribute__((aligned(16))) unsigned short S0[256 * 40]; // 20 KB
  __shared__ __attribute__((aligned(16))) unsigned short S1[256 * 40]; // 20 KB
  __shared__ __attribute__((aligned(8)))  float2 Pc[160];              // BN (A,B) per o

  const int tid = threadIdx.x;
  const int b = blockIdx.x >> 8;
  const int f = blockIdx.x & 255;
  const size_t gbase = (size_t)b * 64 * 65536 + f * 256;   // (b, c=0, f, t=0)
  const size_t tbase = (size_t)(b * 256 + f) * 8192;       // output tile base

  const int lane = tid & 63;
  const int wid = tid >> 6;
  const int m16 = lane & 15;
  const int quad = lane >> 4;

  // ---- BN param table: Pc[o] = (A, B2) with y = conv*A + B2 ----
  if (tid < 160) {
    const ConvP& P = (tid < 64) ? fqk : (tid < 128) ? tqk : fv;
    const int o = (tid < 64) ? tid : (tid < 128) ? tid - 64 : tid - 128;
    const float A = P.g[o] * rsqrtf(P.v[o] + 1e-5f);
    const float B2 = (P.bi[o] - P.m[o]) * A + P.be[o];
    Pc[tid] = make_float2(A, B2);
  }

  // ---- stage an X tile (fp32 global -> bf16 LDS [c][t], stride 260) ----
  auto load_X = [&](const float* __restrict__ src) {
    #pragma unroll
    for (int r = 0; r < 16; ++r) {
      const int idx = r * 256 + tid;
      const int c = idx >> 6;
      const int t0 = (idx & 63) * 4;
      const float4 v = *(const float4*)(src + gbase + (size_t)c * 65536 + t0);
      unsigned lo = (unsigned)f2bf(v.x) | (((unsigned)f2bf(v.y)) << 16);
      unsigned hi = (unsigned)f2bf(v.z) | (((unsigned)f2bf(v.w)) << 16);
      u32x2 pk = {lo, hi};
      *(u32x2*)&Xb[c * 260 + t0] = pk;
    }
  };

  // ---- A-frag: W[o = ot*16+m16][k = ks*32+quad*8+j] (fp32 global -> bf16) --
  auto load_A = [&](const float* __restrict__ W, int rowbase, int ks) {
    const float* p = W + (rowbase + m16) * 64 + ks * 32 + quad * 8;
    const float4 lo = *(const float4*)p;
    const float4 hi = *(const float4*)(p + 4);
    bf16x8 r;
    r[0] = (short)f2bf(lo.x); r[1] = (short)f2bf(lo.y);
    r[2] = (short)f2bf(lo.z); r[3] = (short)f2bf(lo.w);
    r[4] = (short)f2bf(hi.x); r[5] = (short)f2bf(hi.y);
    r[6] = (short)f2bf(hi.z); r[7] = (short)f2bf(hi.w);
    return r;
  };

  // ---- B-frag: X[t = tt*16+m16][k = ks*32+quad*8+j] from LDS ----
  auto load_B = [&](int tt, int ks) {
    const int t = tt * 16 + m16;
    const int i0 = ks * 32 + quad * 8;
    bf16x8 r;
    #pragma unroll
    for (int j = 0; j < 8; ++j) r[j] = (short)Xb[(i0 + j) * 260 + t];
    return r;
  };

  // ---- stream a staged [256 t][32 ch] (stride 40) buffer out lane-dense ----
  auto emit = [&](const unsigned short* S, bf16* __restrict__ dst) {
    #pragma unroll
    for (int r = 0; r < 4; ++r) {
      const int chunk = r * 256 + tid;           // 16 B units
      const int t = chunk >> 2, part = chunk & 3;
      u32x4 v = *(const u32x4*)&S[t * 40 + part * 8];
      *(u32x4*)(dst + tbase + (size_t)chunk * 8) = v;
    }
  };

  auto leaky = [](float y, float alpha) { return y > 0.f ? y : alpha * y; };

  // ---- qk pass: 64-row matrix, de-interleave even->S0 (Q), odd->S1 (K) ----
  auto qk_pass = [&](const ConvP& P, int pcb) {
    bf16x8 A[4][2];
    #pragma unroll
    for (int ot = 0; ot < 4; ++ot)
      #pragma unroll
      for (int ks = 0; ks < 2; ++ks) A[ot][ks] = load_A(P.W, ot * 16, ks);
    float pA[4][4], pB[4][4];
    #pragma unroll
    for (int ot = 0; ot < 4; ++ot)
      #pragma unroll
      for (int r = 0; r < 4; ++r) {
        const float2 pp = Pc[pcb + ot * 16 + quad * 4 + r];
        pA[ot][r] = pp.x; pB[ot][r] = pp.y;
      }
    const float alpha = P.a[0];
    #pragma unroll
    for (int i = 0; i < 4; ++i) {
      const int tt = wid * 4 + i;
      const bf16x8 B0 = load_B(tt, 0);
      const bf16x8 B1 = load_B(tt, 1);
      const int t = tt * 16 + m16;
      #pragma unroll
      for (int ot = 0; ot < 4; ++ot) {
        f32x4 acc = {0.f, 0.f, 0.f, 0.f};
        acc = __builtin_amdgcn_mfma_f32_16x16x32_bf16(A[ot][0], B0, acc, 0, 0, 0);
        acc = __builtin_amdgcn_mfma_f32_16x16x32_bf16(A[ot][1], B1, acc, 0, 0, 0);
        float y[4];
        #pragma unroll
        for (int r = 0; r < 4; ++r)
          y[r] = leaky(acc[r] * pA[ot][r] + pB[ot][r], alpha);
        // o = ot*16 + quad*4 + r;  even o -> Q ch o/2, odd -> K ch o/2
        const int ch0 = ot * 8 + quad * 2;       // even
        unsigned q = (unsigned)f2bf(y[0]) | (((unsigned)f2bf(y[2])) << 16);
        unsigned k = (unsigned)f2bf(y[1]) | (((unsigned)f2bf(y[3])) << 16);
        *(unsigned*)&S0[t * 40 + ch0] = q;
        *(unsigned*)&S1[t * 40 + ch0] = k;
      }
    }
  };

  // ---- v pass: 32-row matrix -> S0 directly ----
  auto v_pass = [&]() {
    bf16x8 A[2][2];
    #pragma unroll
    for (int ot = 0; ot < 2; ++ot)
      #pragma unroll
      for (int ks = 0; ks < 2; ++ks) A[ot][ks] = load_A(fv.W, ot * 16, ks);
    float pA[2][4], pB[2][4];
    #pragma unroll
    for (int ot = 0; ot < 2; ++ot)
      #pragma unroll
      for (int r = 0; r < 4; ++r) {
        const float2 pp = Pc[128 + ot * 16 + quad * 4 + r];
        pA[ot][r] = pp.x; pB[ot][r] = pp.y;
      }
    const float alpha = fv.a[0];
    #pragma unroll
    for (int i = 0; i < 4; ++i) {
      const int tt = wid * 4 + i;
      const bf16x8 B0 = load_B(tt, 0);
      const bf16x8 B1 = load_B(tt, 1);
      const int t = tt * 16 + m16;
      #pragma unroll
      for (int ot = 0; ot < 2; ++ot) {
        f32x4 acc = {0.f, 0.f, 0.f, 0.f};
        acc = __builtin_amdgcn_mfma_f32_16x16x32_bf16(A[ot][0], B0, acc, 0, 0, 0);
        acc = __builtin_amdgcn_mfma_f32_16x16x32_bf16(A[ot][1], B1, acc, 0, 0, 0);
        float y[4];
        #pragma unroll
        for (int r = 0; r < 4; ++r)
          y[r] = leaky(acc[r] * pA[ot][r] + pB[ot][r], alpha);
        const int ch = ot * 16 + quad * 4;       // ch = o directly
        *(unsigned*)&S0[t * 40 + ch]     = (unsigned)f2bf(y[0]) | (((unsigned)f2bf(y[1])) << 16);
        *(unsigned*)&S0[t * 40 + ch + 2] = (unsigned)f2bf(y[2]) | (((unsigned)f2bf(y[3])) << 16);
      }
    }
  };

  load_X(inp);
  __syncthreads();                 // Xb + Pc ready
  qk_pass(fqk, 0);
  __syncthreads();
  emit(S0, Qf); emit(S1, Kf);
  __syncthreads();
  qk_pass(tqk, 64);
  __syncthreads();
  emit(S0, Qt); emit(S1, Kt);
  __syncthreads();
  load_X(x);                       // overwrite Xb with x tile
  __syncthreads();
  v_pass();
  __syncthreads();
  emit(S0, Vf);
}

// ---------------------------------------------------------------------------
// Attention kernel: 1024 instances of [256 x 256, head dim 32].
// All buffers layout (B,F,T,CH).
//   CAUSAL (t-attn):  instance (b,f): row r at inst*8192 + r*32 (contiguous)
//   !CAUSAL (f-attn): instance (b,t): row r at b*2M + t*32 + r*8192 (strided)
// K staged once per block in LDS; Q loaded per-wave sector-dense via scratch;
// O staged in scratch and streamed out sector-dense.
// ---------------------------------------------------------------------------
template<bool CAUSAL>
__global__ __launch_bounds__(256) void attn_k(
    const bf16* __restrict__ Qg, const bf16* __restrict__ Kg,
    const bf16* __restrict__ Vg, bf16* __restrict__ Og)
{
  __shared__ __attribute__((aligned(16))) unsigned short Kl[256 * 32];       // 16 KB dense
  __shared__ __attribute__((aligned(16))) unsigned short Vt[32 * 264];       // V^T, stride 264
  __shared__ __attribute__((aligned(16))) unsigned short Plds[4][16 * 264];  // per-wave P
  __shared__ __attribute__((aligned(16))) unsigned short Wsc[4][512];        // per-wave Q/O scratch

  const int inst = blockIdx.x;
  const int b = inst >> 8;
  const int s = inst & 255;
  constexpr int RS = CAUSAL ? 32 : 8192;             // row stride (elements)
  const int qbase = CAUSAL ? inst * 8192 : (b * 2097152 + s * 32);

  const int tid = threadIdx.x;
  // ---- stage K tile (sector-dense cooperative load) ----
  #pragma unroll
  for (int k2 = 0; k2 < 4; ++k2) {
    const int chunk = k2 * 256 + tid;            // 0..1023
    const int row = chunk >> 2, part = chunk & 3;
    u32x4 val = *(const u32x4*)(Kg + qbase + row * RS + part * 8);
    *(u32x4*)&Kl[row * 32 + part * 8] = val;
  }
  // ---- stage V transposed ----
  if (tid < 128) {
    const unsigned short* v0 = (const unsigned short*)(Vg + qbase) + (2 * tid) * RS;
    const unsigned short* v1 = v0 + RS;
    u16x8 a[4], c[4];
    #pragma unroll
    for (int q = 0; q < 4; ++q) {
      a[q] = *(const u16x8*)(v0 + 8 * q);
      c[q] = *(const u16x8*)(v1 + 8 * q);
    }
    unsigned int* vt32 = (unsigned int*)Vt;
    #pragma unroll
    for (int cc = 0; cc < 32; ++cc) {
      unsigned lo = a[cc >> 3][cc & 7];
      unsigned hi = c[cc >> 3][cc & 7];
      vt32[(cc * 264 + 2 * tid) >> 1] = lo | (hi << 16);
    }
  }
  __syncthreads();

  const int lane = tid & 63;
  const int wid = tid >> 6;
  const int m16 = lane & 15;
  const int quad = lane >> 4;
  const float sc = 0.17677669529663687f;   // 1/sqrt(32)

  unsigned short* P  = &Plds[wid][0];
  unsigned short* Ws = &Wsc[wid][0];
  const int r4 = lane >> 2, p4 = lane & 3;

  #pragma unroll 1
  for (int it = 0; it < 4; ++it) {
    const int rt = wid + 4 * it;
    // wave loads its Q tile sector-dense into private scratch, then frag-reads
    {
      u32x4 qv = *(const u32x4*)(Qg + qbase + (rt * 16 + r4) * RS + p4 * 8);
      *(u32x4*)&Ws[r4 * 32 + p4 * 8] = qv;
    }
    const bf16x8 qf = *(const bf16x8*)&Ws[m16 * 32 + quad * 8];
    const int nct = CAUSAL ? (rt + 1) : 16;

    f32x4 acc[16];
    #pragma unroll
    for (int ct = 0; ct < 16; ++ct) {
      if (ct < nct) {
        const bf16x8 kf = *(const bf16x8*)&Kl[(ct * 16 + m16) * 32 + quad * 8];
        f32x4 z = {0.f, 0.f, 0.f, 0.f};
        acc[ct] = __builtin_amdgcn_mfma_f32_16x16x32_bf16(qf, kf, z, 0, 0, 0);
      }
    }
    // scale + causal mask + row max (D layout: col=lane&15, row=quad*4+reg)
    float mx[4] = {-3e38f, -3e38f, -3e38f, -3e38f};
    #pragma unroll
    for (int ct = 0; ct < 16; ++ct) if (ct < nct) {
      #pragma unroll
      for (int r = 0; r < 4; ++r) {
        float v = acc[ct][r] * sc;
        if (CAUSAL && (ct == nct - 1) && (m16 > quad * 4 + r)) v = -3e38f;
        acc[ct][r] = v;
        mx[r] = fmaxf(mx[r], v);
      }
    }
    #pragma unroll
    for (int r = 0; r < 4; ++r) {
      float m = mx[r];
      #pragma unroll
      for (int d = 1; d < 16; d <<= 1) m = fmaxf(m, __shfl_xor(m, d, 16));
      mx[r] = m;
    }
    float sum[4] = {0.f, 0.f, 0.f, 0.f};
    #pragma unroll
    for (int ct = 0; ct < 16; ++ct) if (ct < nct) {
      #pragma unroll
      for (int r = 0; r < 4; ++r) {
        float p = __expf(acc[ct][r] - mx[r]);
        acc[ct][r] = p;
        sum[r] += p;
      }
    }
    float inv[4];
    #pragma unroll
    for (int r = 0; r < 4; ++r) {
      float ssum = sum[r];
      #pragma unroll
      for (int d = 1; d < 16; d <<= 1) ssum += __shfl_xor(ssum, d, 16);
      inv[r] = 1.0f / ssum;
    }
    // write normalized P (bf16) to per-wave LDS
    #pragma unroll
    for (int ct = 0; ct < 16; ++ct) if (ct < nct) {
      #pragma unroll
      for (int r = 0; r < 4; ++r)
        P[(quad * 4 + r) * 264 + ct * 16 + m16] = f2bf(acc[ct][r] * inv[r]);
    }
    int ksteps = CAUSAL ? ((rt >> 1) + 1) : 8;
    if (CAUSAL && ((rt & 1) == 0)) {
      // zero-pad tile ct=rt+1 so the K=32 MFMA step covering it reads zeros
      #pragma unroll
      for (int u = 0; u < 4; ++u) {
        const int e = lane + 64 * u;
        P[(e >> 4) * 264 + (rt + 1) * 16 + (e & 15)] = 0;
      }
    }
    // O = P * V  (A-frag: m=lane&15, k=quad*8+j; B-frag from Vt rows)
    f32x4 o0 = {0.f, 0.f, 0.f, 0.f}, o1 = {0.f, 0.f, 0.f, 0.f};
    #pragma unroll
    for (int ks = 0; ks < 8; ++ks) {
      if (ks < ksteps) {
        const bf16x8 pf  = *(const bf16x8*)&P[m16 * 264 + ks * 32 + quad * 8];
        const bf16x8 vf0 = *(const bf16x8*)&Vt[m16 * 264 + ks * 32 + quad * 8];
        const bf16x8 vf1 = *(const bf16x8*)&Vt[(16 + m16) * 264 + ks * 32 + quad * 8];
        o0 = __builtin_amdgcn_mfma_f32_16x16x32_bf16(pf, vf0, o0, 0, 0, 0);
        o1 = __builtin_amdgcn_mfma_f32_16x16x32_bf16(pf, vf1, o1, 0, 0, 0);
      }
    }
    // stage O tile in per-wave scratch, stream out sector-dense
    #pragma unroll
    for (int r = 0; r < 4; ++r) {
      Ws[(quad * 4 + r) * 32 + m16]      = f2bf(o0[r]);
      Ws[(quad * 4 + r) * 32 + 16 + m16] = f2bf(o1[r]);
    }
    {
      u32x4 ov = *(const u32x4*)&Ws[r4 * 32 + p4 * 8];
      *(u32x4*)(Og + qbase + (rt * 16 + r4) * RS + p4 * 8) = ov;
    }
  }
}

// ---------------------------------------------------------------------------
// Kernel D: proj conv (32->64) + BN + LeakyReLU + residual add. fp32 output.
// ---------------------------------------------------------------------------
__global__ __launch_bounds__(256) void proj_k(
    const bf16* __restrict__ tout, const float* __restrict__ x,
    ConvP pj, float* __restrict__ out)
{
  const int tid = threadIdx.x;
  const int b = blockIdx.x >> 8;
  const int f = blockIdx.x & 255;
  const unsigned short* tp =
      (const unsigned short*)tout + ((b * 256 + f) * 256 + tid) * 32;
  u16x8 tv[4];
  #pragma unroll
  for (int q = 0; q < 4; ++q) tv[q] = *(const u16x8*)(tp + 8 * q);
  float vin[32];
  #pragma unroll
  for (int c = 0; c < 32; ++c) vin[c] = bf2f(tv[c >> 3][c & 7]);
  const float alpha = pj.a[0];
  const int xoff = b * 64 * 65536 + f * 256 + tid;
  #pragma unroll 4
  for (int o = 0; o < 64; ++o) {
    float acc = 0.f;
    #pragma unroll
    for (int i = 0; i < 32; ++i) acc += pj.W[o * 32 + i] * vin[i];
    const float s = rsqrtf(pj.v[o] + 1e-5f);
    const float A = pj.g[o] * s;
    float y = (acc + pj.bi[o] - pj.m[o]) * A + pj.be[o];
    y = y > 0.f ? y : alpha * y;
    out[xoff + o * 65536] = y + x[xoff + o * 65536];
  }
}

extern "C" void kernel_launch(void* const* d_in, const int* in_sizes, int n_in,
                              void* d_out, int out_size, void* d_ws, size_t ws_size,
                              hipStream_t stream) {
  const float* inp = (const float*)d_in[0];
  const float* x   = (const float*)d_in[1];
  auto cp = [&](int i) {
    return ConvP{ (const float*)d_in[i],     (const float*)d_in[i + 1],
                  (const float*)d_in[i + 2], (const float*)d_in[i + 3],
                  (const float*)d_in[i + 4], (const float*)d_in[i + 5],
                  (const float*)d_in[i + 6] };
  };
  ConvP fqk = cp(2), fv = cp(9), tqk = cp(16), pj = cp(23);

  char* ws = (char*)d_ws;
  const size_t SZ = (size_t)4 * 256 * 256 * 32 * 2;  // 16 MiB per bf16 buffer
  bf16* Qf = (bf16*)(ws + 0 * SZ);   // (B,F,T,CH)
  bf16* Kf = (bf16*)(ws + 1 * SZ);
  bf16* Vf = (bf16*)(ws + 2 * SZ);
  bf16* Qt = (bf16*)(ws + 3 * SZ);
  bf16* Kt = (bf16*)(ws + 4 * SZ);
  bf16* Ft = (bf16*)(ws + 5 * SZ);   // fout (B,F,T,CH)
  bf16* To = (bf16*)(ws + 0 * SZ);   // tout reuses Qf (dead after f-attn)

  conv_qkv<<<1024, 256, 0, stream>>>(inp, x, fqk, fv, tqk, Qf, Kf, Vf, Qt, Kt);
  attn_k<false><<<1024, 256, 0, stream>>>(Qf, Kf, Vf, Ft);   // freq attention
  attn_k<true><<<1024, 256, 0, stream>>>(Qt, Kt, Ft, To);    // causal time attention
  proj_k<<<1024, 256, 0, stream>>>(To, x, pj, (float*)d_out);
}

// Round 5
// 327.788 us; speedup vs baseline: 2.0480x; 1.0853x over previous
//
#include <hip/hip_runtime.h>
#include <hip/hip_bf16.h>

// Problem constants: B=4, C=64, F=256, T=256, CH=32
typedef __hip_bfloat16 bf16;
typedef __attribute__((ext_vector_type(8))) short bf16x8;
typedef __attribute__((ext_vector_type(4))) float f32x4;
typedef __attribute__((ext_vector_type(16))) float f32x16;
typedef __attribute__((ext_vector_type(8))) unsigned short u16x8;
typedef __attribute__((ext_vector_type(4))) unsigned int u32x4;
typedef __attribute__((ext_vector_type(2))) unsigned int u32x2;

struct ConvP {
  const float* W; const float* bi; const float* g; const float* be;
  const float* m; const float* v; const float* a;
};

// 1/sqrt(32) * log2(e): folded into Q-channel BN params (leaky ReLU is
// positively homogeneous so scale commutes); attention then uses raw exp2.
#define QS (0.17677669529663687f * 1.4426950408889634f)

__device__ __forceinline__ unsigned short f2bf(float f) {
  __hip_bfloat16 h = __float2bfloat16(f);
  return __builtin_bit_cast(unsigned short, h);
}
__device__ __forceinline__ float bf2f(unsigned short u) {
  return __uint_as_float(((unsigned)u) << 16);
}
__device__ __forceinline__ float fast_exp2(float x) {
#if __has_builtin(__builtin_amdgcn_exp2f)
  return __builtin_amdgcn_exp2f(x);
#else
  return exp2f(x);
#endif
}

// ---------------------------------------------------------------------------
// Kernel A (v5): fused 1x1 conv + BN + LeakyReLU via 16x16x32 MFMA.
// v5 deltas: B-fragments hoisted once (fqk+tqk share the X tile; halves the
// scalar LDS reads that dominated v4's latency), QS folded into Q channels.
// ---------------------------------------------------------------------------
__global__ __launch_bounds__(256, 2) void conv_qkv(
    const float* __restrict__ inp, const float* __restrict__ x,
    ConvP fqk, ConvP fv, ConvP tqk,
    bf16* __restrict__ Qf, bf16* __restrict__ Kf, bf16* __restrict__ Vf,
    bf16* __restrict__ Qt, bf16* __restrict__ Kt)
{
  __shared__ __attribute__((aligned(16))) unsigned short Xb[64 * 260]; // 33.3 KB
  __shared__ __attribute__((aligned(16))) unsigned short S0[256 * 40]; // 20 KB
  __shared__ __attribute__((aligned(16))) unsigned short S1[256 * 40]; // 20 KB
  __shared__ __attribute__((aligned(8)))  float2 Pc[160];              // BN (A,B) per o

  const int tid = threadIdx.x;
  const int b = blockIdx.x >> 8;
  const int f = blockIdx.x & 255;
  const size_t gbase = (size_t)b * 64 * 65536 + f * 256;   // (b, c=0, f, t=0)
  const size_t tbase = (size_t)(b * 256 + f) * 8192;       // output tile base

  const int lane = tid & 63;
  const int wid = tid >> 6;
  const int m16 = lane & 15;
  const int quad = lane >> 4;

  // ---- BN param table: Pc[o] = (A, B2) with y = conv*A + B2 ----
  if (tid < 160) {
    const ConvP& P = (tid < 64) ? fqk : (tid < 128) ? tqk : fv;
    const int o = (tid < 64) ? tid : (tid < 128) ? tid - 64 : tid - 128;
    float A = P.g[o] * rsqrtf(P.v[o] + 1e-5f);
    float B2 = (P.bi[o] - P.m[o]) * A + P.be[o];
    if (tid < 128 && ((o & 1) == 0)) { A *= QS; B2 *= QS; }  // Q channels
    Pc[tid] = make_float2(A, B2);
  }

  // ---- stage an X tile (fp32 global -> bf16 LDS [c][t], stride 260) ----
  auto load_X = [&](const float* __restrict__ src) {
    #pragma unroll
    for (int r = 0; r < 16; ++r) {
      const int idx = r * 256 + tid;
      const int c = idx >> 6;
      const int t0 = (idx & 63) * 4;
      const float4 v = *(const float4*)(src + gbase + (size_t)c * 65536 + t0);
      unsigned lo = (unsigned)f2bf(v.x) | (((unsigned)f2bf(v.y)) << 16);
      unsigned hi = (unsigned)f2bf(v.z) | (((unsigned)f2bf(v.w)) << 16);
      u32x2 pk = {lo, hi};
      *(u32x2*)&Xb[c * 260 + t0] = pk;
    }
  };

  // ---- A-frag: W[o = rowbase+m16][k = ks*32+quad*8+j] (fp32 -> bf16) ----
  auto load_A = [&](const float* __restrict__ W, int rowbase, int ks) {
    const float* p = W + (rowbase + m16) * 64 + ks * 32 + quad * 8;
    const float4 lo = *(const float4*)p;
    const float4 hi = *(const float4*)(p + 4);
    bf16x8 r;
    r[0] = (short)f2bf(lo.x); r[1] = (short)f2bf(lo.y);
    r[2] = (short)f2bf(lo.z); r[3] = (short)f2bf(lo.w);
    r[4] = (short)f2bf(hi.x); r[5] = (short)f2bf(hi.y);
    r[6] = (short)f2bf(hi.z); r[7] = (short)f2bf(hi.w);
    return r;
  };

  // ---- B-frag: X[t = tt*16+m16][k = ks*32+quad*8+j] from LDS ----
  auto load_B = [&](int tt, int ks) {
    const int t = tt * 16 + m16;
    const int i0 = ks * 32 + quad * 8;
    bf16x8 r;
    #pragma unroll
    for (int j = 0; j < 8; ++j) r[j] = (short)Xb[(i0 + j) * 260 + t];
    return r;
  };

  // ---- stream a staged [256 t][32 ch] (stride 40) buffer out lane-dense ----
  auto emit = [&](const unsigned short* S, bf16* __restrict__ dst) {
    #pragma unroll
    for (int r = 0; r < 4; ++r) {
      const int chunk = r * 256 + tid;           // 16 B units
      const int t = chunk >> 2, part = chunk & 3;
      u32x4 v = *(const u32x4*)&S[t * 40 + part * 8];
      *(u32x4*)(dst + tbase + (size_t)chunk * 8) = v;
    }
  };

  auto leaky = [](float y, float alpha) { return y > 0.f ? y : alpha * y; };

  // ---- qk pass: 64-row matrix, de-interleave even->S0 (Q), odd->S1 (K) ----
  auto qk_pass = [&](const ConvP& P, int pcb, const bf16x8 (&Bf)[4][2]) {
    bf16x8 A[4][2];
    #pragma unroll
    for (int ot = 0; ot < 4; ++ot)
      #pragma unroll
      for (int ks = 0; ks < 2; ++ks) A[ot][ks] = load_A(P.W, ot * 16, ks);
    float pA[4][4], pB[4][4];
    #pragma unroll
    for (int ot = 0; ot < 4; ++ot)
      #pragma unroll
      for (int r = 0; r < 4; ++r) {
        const float2 pp = Pc[pcb + ot * 16 + quad * 4 + r];
        pA[ot][r] = pp.x; pB[ot][r] = pp.y;
      }
    const float alpha = P.a[0];
    #pragma unroll
    for (int i = 0; i < 4; ++i) {
      const int t = (wid * 4 + i) * 16 + m16;
      #pragma unroll
      for (int ot = 0; ot < 4; ++ot) {
        f32x4 acc = {0.f, 0.f, 0.f, 0.f};
        acc = __builtin_amdgcn_mfma_f32_16x16x32_bf16(A[ot][0], Bf[i][0], acc, 0, 0, 0);
        acc = __builtin_amdgcn_mfma_f32_16x16x32_bf16(A[ot][1], Bf[i][1], acc, 0, 0, 0);
        float y[4];
        #pragma unroll
        for (int r = 0; r < 4; ++r)
          y[r] = leaky(acc[r] * pA[ot][r] + pB[ot][r], alpha);
        // o = ot*16 + quad*4 + r;  even o -> Q ch o/2, odd -> K ch o/2
        const int ch0 = ot * 8 + quad * 2;
        *(unsigned*)&S0[t * 40 + ch0] = (unsigned)f2bf(y[0]) | (((unsigned)f2bf(y[2])) << 16);
        *(unsigned*)&S1[t * 40 + ch0] = (unsigned)f2bf(y[1]) | (((unsigned)f2bf(y[3])) << 16);
      }
    }
  };

  load_X(inp);
  __syncthreads();                 // Xb + Pc ready

  bf16x8 Bf[4][2];
  #pragma unroll
  for (int i = 0; i < 4; ++i)
    #pragma unroll
    for (int ks = 0; ks < 2; ++ks) Bf[i][ks] = load_B(wid * 4 + i, ks);

  qk_pass(fqk, 0, Bf);
  __syncthreads();
  emit(S0, Qf); emit(S1, Kf);
  __syncthreads();
  qk_pass(tqk, 64, Bf);
  __syncthreads();
  emit(S0, Qt); emit(S1, Kt);
  __syncthreads();
  load_X(x);                       // overwrite Xb with x tile
  __syncthreads();

  // ---- v pass: 32-row matrix -> S0 ----
  {
    bf16x8 A[2][2], Bv[4][2];
    #pragma unroll
    for (int i = 0; i < 4; ++i)
      #pragma unroll
      for (int ks = 0; ks < 2; ++ks) Bv[i][ks] = load_B(wid * 4 + i, ks);
    #pragma unroll
    for (int ot = 0; ot < 2; ++ot)
      #pragma unroll
      for (int ks = 0; ks < 2; ++ks) A[ot][ks] = load_A(fv.W, ot * 16, ks);
    float pA[2][4], pB[2][4];
    #pragma unroll
    for (int ot = 0; ot < 2; ++ot)
      #pragma unroll
      for (int r = 0; r < 4; ++r) {
        const float2 pp = Pc[128 + ot * 16 + quad * 4 + r];
        pA[ot][r] = pp.x; pB[ot][r] = pp.y;
      }
    const float alpha = fv.a[0];
    #pragma unroll
    for (int i = 0; i < 4; ++i) {
      const int t = (wid * 4 + i) * 16 + m16;
      #pragma unroll
      for (int ot = 0; ot < 2; ++ot) {
        f32x4 acc = {0.f, 0.f, 0.f, 0.f};
        acc = __builtin_amdgcn_mfma_f32_16x16x32_bf16(A[ot][0], Bv[i][0], acc, 0, 0, 0);
        acc = __builtin_amdgcn_mfma_f32_16x16x32_bf16(A[ot][1], Bv[i][1], acc, 0, 0, 0);
        float y[4];
        #pragma unroll
        for (int r = 0; r < 4; ++r)
          y[r] = leaky(acc[r] * pA[ot][r] + pB[ot][r], alpha);
        const int ch = ot * 16 + quad * 4;
        *(unsigned*)&S0[t * 40 + ch]     = (unsigned)f2bf(y[0]) | (((unsigned)f2bf(y[1])) << 16);
        *(unsigned*)&S0[t * 40 + ch + 2] = (unsigned)f2bf(y[2]) | (((unsigned)f2bf(y[3])) << 16);
      }
    }
  }
  __syncthreads();
  emit(S0, Vf);
}

// ---------------------------------------------------------------------------
// Attention kernel (v5): 1024 instances of [256 x 256, head dim 32].
//   CAUSAL (t-attn):  instance (b,f): row r at inst*8192 + r*32 (contiguous)
//   !CAUSAL (f-attn): instance (b,t): row r at b*2M + t*32 + r*8192 (strided)
// v5 deltas vs v4 (all LDS rows were 64 B stride -> 8-way bank conflicts on
// every b128 access):
//  - Kl / Ws padded to stride 40 shorts (2-way = free)
//  - K fragments hoisted into VGPRs once per wave (were re-read 4x)
//  - Q pre-scaled by 1/sqrt(32)*log2e at conv time -> raw exp2, no scale mul
//  - softmax normalization folded into O epilogue (64 muls -> 8)
// ---------------------------------------------------------------------------
template<bool CAUSAL>
__global__ __launch_bounds__(256, 2) void attn_k(
    const bf16* __restrict__ Qg, const bf16* __restrict__ Kg,
    const bf16* __restrict__ Vg, bf16* __restrict__ Og)
{
  __shared__ __attribute__((aligned(16))) unsigned short Kl[256 * 40];       // 20 KB, padded
  __shared__ __attribute__((aligned(16))) unsigned short Vt[32 * 264];       // V^T, stride 264
  __shared__ __attribute__((aligned(16))) unsigned short Plds[4][16 * 264];  // per-wave P
  __shared__ __attribute__((aligned(16))) unsigned short Wsc[4][16 * 40];    // per-wave Q/O scratch

  const int inst = blockIdx.x;
  const int b = inst >> 8;
  const int s = inst & 255;
  constexpr int RS = CAUSAL ? 32 : 8192;             // row stride (elements)
  const int qbase = CAUSAL ? inst * 8192 : (b * 2097152 + s * 32);

  const int tid = threadIdx.x;
  // ---- stage K tile (sector-dense cooperative load, padded rows) ----
  #pragma unroll
  for (int k2 = 0; k2 < 4; ++k2) {
    const int chunk = k2 * 256 + tid;            // 0..1023
    const int row = chunk >> 2, part = chunk & 3;
    u32x4 val = *(const u32x4*)(Kg + qbase + row * RS + part * 8);
    *(u32x4*)&Kl[row * 40 + part * 8] = val;
  }
  // ---- stage V transposed ----
  if (tid < 128) {
    const unsigned short* v0 = (const unsigned short*)(Vg + qbase) + (2 * tid) * RS;
    const unsigned short* v1 = v0 + RS;
    u16x8 a[4], c[4];
    #pragma unroll
    for (int q = 0; q < 4; ++q) {
      a[q] = *(const u16x8*)(v0 + 8 * q);
      c[q] = *(const u16x8*)(v1 + 8 * q);
    }
    unsigned int* vt32 = (unsigned int*)Vt;
    #pragma unroll
    for (int cc = 0; cc < 32; ++cc) {
      unsigned lo = a[cc >> 3][cc & 7];
      unsigned hi = c[cc >> 3][cc & 7];
      vt32[(cc * 264 + 2 * tid) >> 1] = lo | (hi << 16);
    }
  }
  __syncthreads();

  const int lane = tid & 63;
  const int wid = tid >> 6;
  const int m16 = lane & 15;
  const int quad = lane >> 4;

  unsigned short* P  = &Plds[wid][0];
  unsigned short* Ws = &Wsc[wid][0];
  const int r4 = lane >> 2, p4 = lane & 3;

  // ---- hoist all 16 K fragments into VGPRs (read once, used 4x) ----
  bf16x8 kfr[16];
  #pragma unroll
  for (int ct = 0; ct < 16; ++ct)
    kfr[ct] = *(const bf16x8*)&Kl[(ct * 16 + m16) * 40 + quad * 8];

  #pragma unroll 1
  for (int it = 0; it < 4; ++it) {
    const int rt = wid + 4 * it;
    // wave loads its Q tile sector-dense into private scratch, then frag-reads
    {
      u32x4 qv = *(const u32x4*)(Qg + qbase + (rt * 16 + r4) * RS + p4 * 8);
      *(u32x4*)&Ws[r4 * 40 + p4 * 8] = qv;
    }
    const bf16x8 qf = *(const bf16x8*)&Ws[m16 * 40 + quad * 8];
    const int nct = CAUSAL ? (rt + 1) : 16;

    f32x4 acc[16];
    #pragma unroll
    for (int ct = 0; ct < 16; ++ct) {
      if (ct < nct) {
        f32x4 z = {0.f, 0.f, 0.f, 0.f};
        acc[ct] = __builtin_amdgcn_mfma_f32_16x16x32_bf16(qf, kfr[ct], z, 0, 0, 0);
      }
    }
    // causal mask + row max (D layout: col=lane&15, row=quad*4+reg).
    // Logits already in log2 domain (QS folded into Q at conv time).
    float mx[4] = {-3e38f, -3e38f, -3e38f, -3e38f};
    #pragma unroll
    for (int ct = 0; ct < 16; ++ct) if (ct < nct) {
      #pragma unroll
      for (int r = 0; r < 4; ++r) {
        float v = acc[ct][r];
        if (CAUSAL && (ct == nct - 1) && (m16 > quad * 4 + r)) v = -3e38f;
        acc[ct][r] = v;
        mx[r] = fmaxf(mx[r], v);
      }
    }
    #pragma unroll
    for (int r = 0; r < 4; ++r) {
      float m = mx[r];
      #pragma unroll
      for (int d = 1; d < 16; d <<= 1) m = fmaxf(m, __shfl_xor(m, d, 16));
      mx[r] = m;
    }
    float sum[4] = {0.f, 0.f, 0.f, 0.f};
    #pragma unroll
    for (int ct = 0; ct < 16; ++ct) if (ct < nct) {
      #pragma unroll
      for (int r = 0; r < 4; ++r) {
        float p = fast_exp2(acc[ct][r] - mx[r]);
        acc[ct][r] = p;
        sum[r] += p;
      }
    }
    float inv[4];
    #pragma unroll
    for (int r = 0; r < 4; ++r) {
      float ssum = sum[r];
      #pragma unroll
      for (int d = 1; d < 16; d <<= 1) ssum += __shfl_xor(ssum, d, 16);
      inv[r] = 1.0f / ssum;
    }
    // write UNNORMALIZED P (bf16) to per-wave LDS; inv applied in epilogue
    #pragma unroll
    for (int ct = 0; ct < 16; ++ct) if (ct < nct) {
      #pragma unroll
      for (int r = 0; r < 4; ++r)
        P[(quad * 4 + r) * 264 + ct * 16 + m16] = f2bf(acc[ct][r]);
    }
    int ksteps = CAUSAL ? ((rt >> 1) + 1) : 8;
    if (CAUSAL && ((rt & 1) == 0)) {
      // zero-pad tile ct=rt+1 so the K=32 MFMA step covering it reads zeros
      #pragma unroll
      for (int u = 0; u < 4; ++u) {
        const int e = lane + 64 * u;
        P[(e >> 4) * 264 + (rt + 1) * 16 + (e & 15)] = 0;
      }
    }
    // O = P * V  (A-frag: m=lane&15, k=quad*8+j; B-frag from Vt rows)
    f32x4 o0 = {0.f, 0.f, 0.f, 0.f}, o1 = {0.f, 0.f, 0.f, 0.f};
    #pragma unroll
    for (int ks = 0; ks < 8; ++ks) {
      if (ks < ksteps) {
        const bf16x8 pf  = *(const bf16x8*)&P[m16 * 264 + ks * 32 + quad * 8];
        const bf16x8 vf0 = *(const bf16x8*)&Vt[m16 * 264 + ks * 32 + quad * 8];
        const bf16x8 vf1 = *(const bf16x8*)&Vt[(16 + m16) * 264 + ks * 32 + quad * 8];
        o0 = __builtin_amdgcn_mfma_f32_16x16x32_bf16(pf, vf0, o0, 0, 0, 0);
        o1 = __builtin_amdgcn_mfma_f32_16x16x32_bf16(pf, vf1, o1, 0, 0, 0);
      }
    }
    // stage O tile (normalized here) in per-wave scratch, stream out dense
    #pragma unroll
    for (int r = 0; r < 4; ++r) {
      Ws[(quad * 4 + r) * 40 + m16]      = f2bf(o0[r] * inv[r]);
      Ws[(quad * 4 + r) * 40 + 16 + m16] = f2bf(o1[r] * inv[r]);
    }
    {
      u32x4 ov = *(const u32x4*)&Ws[r4 * 40 + p4 * 8];
      *(u32x4*)(Og + qbase + (rt * 16 + r4) * RS + p4 * 8) = ov;
    }
  }
}

// ---------------------------------------------------------------------------
// Kernel D (v5): proj conv (32->64) + BN + LeakyReLU + residual, via
// 32x32x16 MFMA. No LDS (except 512 B BN table): B-frags (tout) and x loads
// come straight from global (row-dense), D stores are full 128 B lines
// (32 consecutive-t lanes). C/D layout [m74/m101]: col=lane&31,
// row=(reg&3)+8*(reg>>2)+4*(lane>>5).
// ---------------------------------------------------------------------------
__global__ __launch_bounds__(256) void proj_k(
    const bf16* __restrict__ tout, const float* __restrict__ x,
    ConvP pj, float* __restrict__ out)
{
  __shared__ float2 Pc[64];
  const int tid = threadIdx.x;
  const int b = blockIdx.x >> 8;
  const int f = blockIdx.x & 255;
  if (tid < 64) {
    const float A = pj.g[tid] * rsqrtf(pj.v[tid] + 1e-5f);
    const float B2 = (pj.bi[tid] - pj.m[tid]) * A + pj.be[tid];
    Pc[tid] = make_float2(A, B2);
  }
  const int lane = tid & 63;
  const int wid = tid >> 6;
  const int n32 = lane & 31;
  const int h = lane >> 5;          // k-half selector

  // A-frags: W[o = ot*32+n32][k = ks*16 + h*8 + j]  (fp32 -> bf16)
  bf16x8 Afr[2][2];
  #pragma unroll
  for (int ot = 0; ot < 2; ++ot)
    #pragma unroll
    for (int ks = 0; ks < 2; ++ks) {
      const float* p = pj.W + (ot * 32 + n32) * 32 + ks * 16 + h * 8;
      const float4 lo = *(const float4*)p;
      const float4 hi = *(const float4*)(p + 4);
      bf16x8 r;
      r[0] = (short)f2bf(lo.x); r[1] = (short)f2bf(lo.y);
      r[2] = (short)f2bf(lo.z); r[3] = (short)f2bf(lo.w);
      r[4] = (short)f2bf(hi.x); r[5] = (short)f2bf(hi.y);
      r[6] = (short)f2bf(hi.z); r[7] = (short)f2bf(hi.w);
      Afr[ot][ks] = r;
    }
  __syncthreads();

  const float alpha = pj.a[0];
  const size_t gbase = (size_t)b * 64 * 65536 + f * 256;  // x/out: + o*65536 + t
  const size_t tbase = (size_t)(b * 256 + f) * 8192;      // tout tile base

  #pragma unroll
  for (int tt = 0; tt < 2; ++tt) {
    const int t = wid * 64 + tt * 32 + n32;
    // B-frags: tout[t][k = ks*16 + h*8 + j] — direct global, rows contiguous
    const bf16x8 B0 = *(const bf16x8*)(tout + tbase + (size_t)t * 32 + 0 * 16 + h * 8);
    const bf16x8 B1 = *(const bf16x8*)(tout + tbase + (size_t)t * 32 + 1 * 16 + h * 8);
    #pragma unroll
    for (int ot = 0; ot < 2; ++ot) {
      f32x16 acc = {};
      acc = __builtin_amdgcn_mfma_f32_32x32x16_bf16(Afr[ot][0], B0, acc, 0, 0, 0);
      acc = __builtin_amdgcn_mfma_f32_32x32x16_bf16(Afr[ot][1], B1, acc, 0, 0, 0);
      #pragma unroll
      for (int reg = 0; reg < 16; ++reg) {
        const int o = ot * 32 + (reg & 3) + 8 * (reg >> 2) + 4 * h;
        const float2 pp = Pc[o];
        float y = acc[reg] * pp.x + pp.y;
        y = y > 0.f ? y : alpha * y;
        const size_t off = gbase + (size_t)o * 65536 + t;
        out[off] = y + x[off];
      }
    }
  }
}

extern "C" void kernel_launch(void* const* d_in, const int* in_sizes, int n_in,
                              void* d_out, int out_size, void* d_ws, size_t ws_size,
                              hipStream_t stream) {
  const float* inp = (const float*)d_in[0];
  const float* x   = (const float*)d_in[1];
  auto cp = [&](int i) {
    return ConvP{ (const float*)d_in[i],     (const float*)d_in[i + 1],
                  (const float*)d_in[i + 2], (const float*)d_in[i + 3],
                  (const float*)d_in[i + 4], (const float*)d_in[i + 5],
                  (const float*)d_in[i + 6] };
  };
  ConvP fqk = cp(2), fv = cp(9), tqk = cp(16), pj = cp(23);

  char* ws = (char*)d_ws;
  const size_t SZ = (size_t)4 * 256 * 256 * 32 * 2;  // 16 MiB per bf16 buffer
  bf16* Qf = (bf16*)(ws + 0 * SZ);   // (B,F,T,CH)
  bf16* Kf = (bf16*)(ws + 1 * SZ);
  bf16* Vf = (bf16*)(ws + 2 * SZ);
  bf16* Qt = (bf16*)(ws + 3 * SZ);
  bf16* Kt = (bf16*)(ws + 4 * SZ);
  bf16* Ft = (bf16*)(ws + 5 * SZ);   // fout (B,F,T,CH)
  bf16* To = (bf16*)(ws + 0 * SZ);   // tout reuses Qf (dead after f-attn)

  conv_qkv<<<1024, 256, 0, stream>>>(inp, x, fqk, fv, tqk, Qf, Kf, Vf, Qt, Kt);
  attn_k<false><<<1024, 256, 0, stream>>>(Qf, Kf, Vf, Ft);   // freq attention
  attn_k<true><<<1024, 256, 0, stream>>>(Qt, Kt, Ft, To);    // causal time attention
  proj_k<<<1024, 256, 0, stream>>>(To, x, pj, (float*)d_out);
}